// Round 1
// baseline (15031.244 us; speedup 1.0000x reference)
//
#include <hip/hip_runtime.h>
#include <math.h>

#define T_STEPS 168
#define INP     19
#define HID     64
#define G4      256
#define ROWS    16
#define NTHREADS 256

__device__ __forceinline__ float fast_sigmoid(float x) {
    // 1/(1+e^-x); rcp is ~1 ulp, fine vs 1.1e-3 budget
    return __builtin_amdgcn_rcpf(1.0f + __expf(-x));
}
__device__ __forceinline__ float fast_tanh(float x) {
    // 1 - 2/(e^{2x}+1); handles +/-inf saturation correctly
    return 1.0f - 2.0f * __builtin_amdgcn_rcpf(1.0f + __expf(2.0f * x));
}

__global__ __launch_bounds__(NTHREADS, 1)
void lstm2_fused_kernel(const float* __restrict__ x,
                        const float* __restrict__ Wih0,
                        const float* __restrict__ Whh0,
                        const float* __restrict__ bih0,
                        const float* __restrict__ bhh0,
                        const float* __restrict__ Wih1,
                        const float* __restrict__ Whh1,
                        const float* __restrict__ bih1,
                        const float* __restrict__ bhh1,
                        const float* __restrict__ Wfc,
                        const float* __restrict__ bfc,
                        float* __restrict__ out)
{
    // row stride 68 (not 64): bank offset 4*r per row -> no 4-way conflict on b128 reads
    __shared__ float xs [ROWS][20];
    __shared__ float h1s[ROWS][68];
    __shared__ float h2s[ROWS][68];
    __shared__ float c1s[ROWS][68];
    __shared__ float c2s[ROWS][68];
    __shared__ float bsum1[G4];
    __shared__ float bsum2[G4];

    const int tid = threadIdx.x;
    const int r   = tid >> 4;     // 0..15: batch row within tile
    const int q   = tid & 15;     // 0..15: unit block
    const int u0  = q << 2;       // first of my 4 hidden units
    const int b0  = blockIdx.x * ROWS;

    bsum1[tid] = bih0[tid] + bhh0[tid];
    bsum2[tid] = bih1[tid] + bhh1[tid];
#pragma unroll
    for (int j = 0; j < 4; ++j) {
        h1s[r][u0 + j] = 0.0f; h2s[r][u0 + j] = 0.0f;
        c1s[r][u0 + j] = 0.0f; c2s[r][u0 + j] = 0.0f;
    }
    __syncthreads();

    for (int t = 0; t < T_STEPS; ++t) {
        // ---- stage x tile [16][19] into LDS (304 elems, <=2 per thread) ----
        {
            int e = tid;
            if (e < ROWS * INP) {
                int rr = e / INP, ii = e - rr * INP;
                xs[rr][ii] = x[((b0 + rr) * T_STEPS + t) * INP + ii];
            }
            e = tid + NTHREADS;
            if (e < ROWS * INP) {
                int rr = e / INP, ii = e - rr * INP;
                xs[rr][ii] = x[((b0 + rr) * T_STEPS + t) * INP + ii];
            }
        }
        // ---- read h1(t-1) into regs (before B1: read-before-overwrite) ----
        float hp[HID];
        {
            const float4* p = (const float4*)(&h1s[r][0]);
#pragma unroll
            for (int k = 0; k < 16; ++k) {
                const float4 v = p[k];
                hp[4*k+0] = v.x; hp[4*k+1] = v.y; hp[4*k+2] = v.z; hp[4*k+3] = v.w;
            }
        }
        __syncthreads();   // B1: xs visible; all h1s reads done

        // x row into regs
        float xr[INP];
        {
            const float4* p = (const float4*)(&xs[r][0]);
#pragma unroll
            for (int k = 0; k < 4; ++k) {
                const float4 v = p[k];
                xr[4*k+0] = v.x; xr[4*k+1] = v.y; xr[4*k+2] = v.z; xr[4*k+3] = v.w;
            }
            xr[16] = xs[r][16]; xr[17] = xs[r][17]; xr[18] = xs[r][18];
        }

        // ---- layer 1: my 4 units, 4 gates each ----
        for (int j = 0; j < 4; ++j) {
            const int u = u0 + j;
            float a4[4];
#pragma unroll
            for (int gi = 0; gi < 4; ++gi) {
                const int g = u + (gi << 6);          // gate row (i,f,g,o blocks)
                float a = bsum1[g];
                const float* wi = Wih0 + g * INP;
#pragma unroll
                for (int i = 0; i < INP; ++i) a = fmaf(xr[i], wi[i], a);
                const float4* wh = (const float4*)(Whh0 + g * HID);
#pragma unroll
                for (int k = 0; k < 16; ++k) {
                    const float4 w = wh[k];
                    a = fmaf(hp[4*k+0], w.x, a);
                    a = fmaf(hp[4*k+1], w.y, a);
                    a = fmaf(hp[4*k+2], w.z, a);
                    a = fmaf(hp[4*k+3], w.w, a);
                }
                a4[gi] = a;
            }
            const float ig = fast_sigmoid(a4[0]);
            const float fg = fast_sigmoid(a4[1]);
            const float gg = fast_tanh(a4[2]);
            const float og = fast_sigmoid(a4[3]);
            const float c  = fg * c1s[r][u] + ig * gg;
            c1s[r][u] = c;
            h1s[r][u] = og * fast_tanh(c);
        }
        __syncthreads();   // B2: h1(t) visible

        // ---- layer 2: read h1(t) and h2(t-1) into regs ----
        float ha[HID], hb[HID];
        {
            const float4* p1 = (const float4*)(&h1s[r][0]);
            const float4* p2 = (const float4*)(&h2s[r][0]);
#pragma unroll
            for (int k = 0; k < 16; ++k) {
                const float4 v = p1[k];
                ha[4*k+0] = v.x; ha[4*k+1] = v.y; ha[4*k+2] = v.z; ha[4*k+3] = v.w;
                const float4 w = p2[k];
                hb[4*k+0] = w.x; hb[4*k+1] = w.y; hb[4*k+2] = w.z; hb[4*k+3] = w.w;
            }
        }
        __syncthreads();   // B3: all h2s reads done before h2s writes

        for (int j = 0; j < 4; ++j) {
            const int u = u0 + j;
            float a4[4];
#pragma unroll
            for (int gi = 0; gi < 4; ++gi) {
                const int g = u + (gi << 6);
                float a = bsum2[g];
                const float4* wa = (const float4*)(Wih1 + g * HID);
#pragma unroll
                for (int k = 0; k < 16; ++k) {
                    const float4 w = wa[k];
                    a = fmaf(ha[4*k+0], w.x, a);
                    a = fmaf(ha[4*k+1], w.y, a);
                    a = fmaf(ha[4*k+2], w.z, a);
                    a = fmaf(ha[4*k+3], w.w, a);
                }
                const float4* wb = (const float4*)(Whh1 + g * HID);
#pragma unroll
                for (int k = 0; k < 16; ++k) {
                    const float4 w = wb[k];
                    a = fmaf(hb[4*k+0], w.x, a);
                    a = fmaf(hb[4*k+1], w.y, a);
                    a = fmaf(hb[4*k+2], w.z, a);
                    a = fmaf(hb[4*k+3], w.w, a);
                }
                a4[gi] = a;
            }
            const float ig = fast_sigmoid(a4[0]);
            const float fg = fast_sigmoid(a4[1]);
            const float gg = fast_tanh(a4[2]);
            const float og = fast_sigmoid(a4[3]);
            const float c  = fg * c2s[r][u] + ig * gg;
            c2s[r][u] = c;
            h2s[r][u] = og * fast_tanh(c);
        }
        __syncthreads();   // B4: h2(t) visible; xs free for next t
    }

    // ---- final FC: out[b] = h2[b,T-1,:] . Wfc + bfc ----
    if (tid < ROWS) {
        float a = bfc[0];
#pragma unroll
        for (int k = 0; k < HID; ++k)
            a = fmaf(h2s[tid][k], Wfc[k], a);
        out[b0 + tid] = a;
    }
}

extern "C" void kernel_launch(void* const* d_in, const int* in_sizes, int n_in,
                              void* d_out, int out_size, void* d_ws, size_t ws_size,
                              hipStream_t stream) {
    const float* x    = (const float*)d_in[0];
    const float* Wih0 = (const float*)d_in[1];
    const float* Whh0 = (const float*)d_in[2];
    const float* bih0 = (const float*)d_in[3];
    const float* bhh0 = (const float*)d_in[4];
    const float* Wih1 = (const float*)d_in[5];
    const float* Whh1 = (const float*)d_in[6];
    const float* bih1 = (const float*)d_in[7];
    const float* bhh1 = (const float*)d_in[8];
    const float* Wfc  = (const float*)d_in[9];
    const float* bfc  = (const float*)d_in[10];
    float* out = (float*)d_out;

    const int B = in_sizes[0] / (T_STEPS * INP);   // 4096
    const int grid = B / ROWS;                     // 256 workgroups, 1 per CU

    lstm2_fused_kernel<<<dim3(grid), dim3(NTHREADS), 0, stream>>>(
        x, Wih0, Whh0, bih0, bhh0, Wih1, Whh1, bih1, bhh1, Wfc, bfc, out);
}

// Round 2
// 5266.983 us; speedup vs baseline: 2.8539x; 2.8539x over previous
//
#include <hip/hip_runtime.h>
#include <math.h>

#define T_STEPS 168
#define INP     19
#define HID     64
#define NG      256   // 4*HID gate rows
#define ROWS    16
#define NTH     256
#define ZST     258   // z row stride in floats (float2-aligned; <=2-way banks)

__device__ __forceinline__ float fast_sigmoid(float x) {
    return __builtin_amdgcn_rcpf(1.0f + __expf(-x));
}
__device__ __forceinline__ float fast_tanh(float x) {
    return 1.0f - 2.0f * __builtin_amdgcn_rcpf(1.0f + __expf(2.0f * x));
}

__global__ __launch_bounds__(NTH, 1)
void lstm2_regw_kernel(const float* __restrict__ x,
                       const float* __restrict__ Wih0, const float* __restrict__ Whh0,
                       const float* __restrict__ bih0, const float* __restrict__ bhh0,
                       const float* __restrict__ Wih1, const float* __restrict__ Whh1,
                       const float* __restrict__ bih1, const float* __restrict__ bhh1,
                       const float* __restrict__ Wfc,  const float* __restrict__ bfc,
                       float* __restrict__ out)
{
    __shared__ float xs [ROWS][20];   // row stride 80B, 16B aligned
    __shared__ float h1s[ROWS][68];   // row stride 272B, 16B aligned
    __shared__ float h2s[ROWS][68];
    __shared__ float zsb[ROWS][ZST];  // z[r][g]

    const int tid = threadIdx.x;      // z-role: gate row g = tid
    const int b0  = blockIdx.x * ROWS;

    // ---- weight rows into registers (once; scattered global, one-time cost) ----
    float wi0[INP], wh0[HID], wi1[HID], wh1[HID];
    {
        const float* p = Wih0 + tid * INP;
#pragma unroll
        for (int i = 0; i < INP; ++i) wi0[i] = p[i];
        const float4* qa = (const float4*)(Whh0 + tid * HID);
        const float4* qb = (const float4*)(Wih1 + tid * HID);
        const float4* qc = (const float4*)(Whh1 + tid * HID);
#pragma unroll
        for (int k = 0; k < 16; ++k) {
            float4 v = qa[k];
            wh0[4*k+0]=v.x; wh0[4*k+1]=v.y; wh0[4*k+2]=v.z; wh0[4*k+3]=v.w;
            float4 u = qb[k];
            wi1[4*k+0]=u.x; wi1[4*k+1]=u.y; wi1[4*k+2]=u.z; wi1[4*k+3]=u.w;
            float4 w = qc[k];
            wh1[4*k+0]=w.x; wh1[4*k+1]=w.y; wh1[4*k+2]=w.z; wh1[4*k+3]=w.w;
        }
    }

    // ---- update-role constants: thread handles unit uu, rows rb..rb+3 ----
    const int uu = tid >> 2;          // 0..63
    const int rb = (tid & 3) * 4;     // 0,4,8,12
    float bz1[4], bz2[4];
#pragma unroll
    for (int gi = 0; gi < 4; ++gi) {
        bz1[gi] = bih0[uu + 64*gi] + bhh0[uu + 64*gi];
        bz2[gi] = bih1[uu + 64*gi] + bhh1[uu + 64*gi];
    }
    float c1[4] = {0.f,0.f,0.f,0.f}, c2[4] = {0.f,0.f,0.f,0.f};

    // zero h state
    for (int e = tid; e < ROWS*68; e += NTH) {
        ((float*)h1s)[e] = 0.0f; ((float*)h2s)[e] = 0.0f;
    }

    for (int t = 0; t < T_STEPS; ++t) {
        // ---- P0: stage x tile (304 floats, coalesced-ish) ----
        {
            int e = tid;
            if (e < ROWS*INP) {
                int rr = e / INP, ii = e - rr * INP;
                xs[rr][ii] = x[((size_t)(b0+rr)*T_STEPS + t)*INP + ii];
            }
            e = tid + NTH;
            if (e < ROWS*INP) {
                int rr = e / INP, ii = e - rr * INP;
                xs[rr][ii] = x[((size_t)(b0+rr)*T_STEPS + t)*INP + ii];
            }
        }
        __syncthreads();  // B1: xs(t), h2s(t-1) visible; zsb reads of t-1 done

        // ---- P1: z1[r][g] = Wih0[g].x_r + Whh0[g].h1_r  (no bias here) ----
        for (int r = 0; r < ROWS; ++r) {
            const float4* hp = (const float4*)(&h1s[r][0]);
            const float4* xp = (const float4*)(&xs[r][0]);
            float acc[4] = {0.f,0.f,0.f,0.f};
            // x part: 16 via float4 + 3 scalars, spread over the 4 chains
#pragma unroll
            for (int j = 0; j < 4; ++j) {
                float4 v = xp[j];
                acc[j] = fmaf(v.x, wi0[4*j+0], acc[j]);
                acc[j] = fmaf(v.y, wi0[4*j+1], acc[j]);
                acc[j] = fmaf(v.z, wi0[4*j+2], acc[j]);
                acc[j] = fmaf(v.w, wi0[4*j+3], acc[j]);
            }
            acc[0] = fmaf(xs[r][16], wi0[16], acc[0]);
            acc[1] = fmaf(xs[r][17], wi0[17], acc[1]);
            acc[2] = fmaf(xs[r][18], wi0[18], acc[2]);
            // h part: 4 independent chains of 16
#pragma unroll
            for (int c4 = 0; c4 < 4; ++c4) {
#pragma unroll
                for (int j = 0; j < 4; ++j) {
                    float4 v = hp[c4*4 + j];
                    acc[c4] = fmaf(v.x, wh0[16*c4+4*j+0], acc[c4]);
                    acc[c4] = fmaf(v.y, wh0[16*c4+4*j+1], acc[c4]);
                    acc[c4] = fmaf(v.z, wh0[16*c4+4*j+2], acc[c4]);
                    acc[c4] = fmaf(v.w, wh0[16*c4+4*j+3], acc[c4]);
                }
            }
            zsb[r][tid] = (acc[0]+acc[1]) + (acc[2]+acc[3]);
        }
        __syncthreads();  // B2: z1 visible

        // ---- P2: gate update layer1; c1 in regs; write h1s(t) ----
#pragma unroll
        for (int j = 0; j < 4; ++j) {
            const int r = rb + j;
            float zi = zsb[r][uu]        + bz1[0];
            float zf = zsb[r][uu + 64]   + bz1[1];
            float zg = zsb[r][uu + 128]  + bz1[2];
            float zo = zsb[r][uu + 192]  + bz1[3];
            const float ig = fast_sigmoid(zi);
            const float fg = fast_sigmoid(zf);
            const float gg = fast_tanh(zg);
            const float og = fast_sigmoid(zo);
            c1[j] = fg * c1[j] + ig * gg;
            h1s[r][uu] = og * fast_tanh(c1[j]);
        }
        __syncthreads();  // B3: h1s(t) visible; z1 reads done

        // ---- P3: z2[r][g] = Wih1[g].h1_r(t) + Whh1[g].h2_r(t-1) ----
        for (int r = 0; r < ROWS; ++r) {
            const float4* hp = (const float4*)(&h1s[r][0]);
            const float4* gp = (const float4*)(&h2s[r][0]);
            float acc[4] = {0.f,0.f,0.f,0.f};
#pragma unroll
            for (int c4 = 0; c4 < 4; ++c4) {
#pragma unroll
                for (int j = 0; j < 4; ++j) {
                    float4 v = hp[c4*4 + j];
                    acc[c4] = fmaf(v.x, wi1[16*c4+4*j+0], acc[c4]);
                    acc[c4] = fmaf(v.y, wi1[16*c4+4*j+1], acc[c4]);
                    acc[c4] = fmaf(v.z, wi1[16*c4+4*j+2], acc[c4]);
                    acc[c4] = fmaf(v.w, wi1[16*c4+4*j+3], acc[c4]);
                }
            }
#pragma unroll
            for (int c4 = 0; c4 < 4; ++c4) {
#pragma unroll
                for (int j = 0; j < 4; ++j) {
                    float4 v = gp[c4*4 + j];
                    acc[c4] = fmaf(v.x, wh1[16*c4+4*j+0], acc[c4]);
                    acc[c4] = fmaf(v.y, wh1[16*c4+4*j+1], acc[c4]);
                    acc[c4] = fmaf(v.z, wh1[16*c4+4*j+2], acc[c4]);
                    acc[c4] = fmaf(v.w, wh1[16*c4+4*j+3], acc[c4]);
                }
            }
            zsb[r][tid] = (acc[0]+acc[1]) + (acc[2]+acc[3]);
        }
        __syncthreads();  // B4: z2 visible; h2s reads done

        // ---- P4: gate update layer2; c2 in regs; write h2s(t) ----
#pragma unroll
        for (int j = 0; j < 4; ++j) {
            const int r = rb + j;
            float zi = zsb[r][uu]        + bz2[0];
            float zf = zsb[r][uu + 64]   + bz2[1];
            float zg = zsb[r][uu + 128]  + bz2[2];
            float zo = zsb[r][uu + 192]  + bz2[3];
            const float ig = fast_sigmoid(zi);
            const float fg = fast_sigmoid(zf);
            const float gg = fast_tanh(zg);
            const float og = fast_sigmoid(zo);
            c2[j] = fg * c2[j] + ig * gg;
            h2s[r][uu] = og * fast_tanh(c2[j]);
        }
        // no barrier here: next-t P0 touches only xs; B1 orders everything else
    }
    __syncthreads();

    // ---- FC: out[b] = h2[b,T-1,:] . Wfc + bfc ----
    if (tid < ROWS) {
        float a = bfc[0];
#pragma unroll
        for (int k = 0; k < HID; ++k)
            a = fmaf(h2s[tid][k], Wfc[k], a);
        out[b0 + tid] = a;
    }
}

extern "C" void kernel_launch(void* const* d_in, const int* in_sizes, int n_in,
                              void* d_out, int out_size, void* d_ws, size_t ws_size,
                              hipStream_t stream) {
    const float* x    = (const float*)d_in[0];
    const float* Wih0 = (const float*)d_in[1];
    const float* Whh0 = (const float*)d_in[2];
    const float* bih0 = (const float*)d_in[3];
    const float* bhh0 = (const float*)d_in[4];
    const float* Wih1 = (const float*)d_in[5];
    const float* Whh1 = (const float*)d_in[6];
    const float* bih1 = (const float*)d_in[7];
    const float* bhh1 = (const float*)d_in[8];
    const float* Wfc  = (const float*)d_in[9];
    const float* bfc  = (const float*)d_in[10];
    float* out = (float*)d_out;

    const int B = in_sizes[0] / (T_STEPS * INP);   // 4096
    const int grid = B / ROWS;                     // 256 workgroups

    lstm2_regw_kernel<<<dim3(grid), dim3(NTH), 0, stream>>>(
        x, Wih0, Whh0, bih0, bhh0, Wih1, Whh1, bih1, bhh1, Wfc, bfc, out);
}